// Round 1
// baseline (151.193 us; speedup 1.0000x reference)
//
#include <hip/hip_runtime.h>
#include <math.h>

#define NBATCH 4
#define NV 9
#define DM 64
#define DS 16
// H = W = 32, image = 1024 pixels

// ---------------------------------------------------------------------------
// Kernel 1: fused circular 3x3 convs. 96 "output channels":
//   co in [0,64)  -> delta conv (+bias +dt, softplus)
//   co in [64,80) -> B conv
//   co in [80,96) -> C conv
// Grid: 4(b) * 96(co) * 4(h-tile) = 1536 blocks, 256 thr = 8 rows x 32 cols.
// ---------------------------------------------------------------------------
__global__ __launch_bounds__(256) void conv_kernel(
    const float* __restrict__ u, const float* __restrict__ wd,
    const float* __restrict__ bd, const float* __restrict__ wb,
    const float* __restrict__ wc, const float* __restrict__ dtp,
    float* __restrict__ delta_out, float* __restrict__ Bv_out,
    float* __restrict__ Cv_out)
{
    int bx = blockIdx.x;
    int ht = bx & 3;
    int co = (bx >> 2) % 96;
    int b  = bx / (4 * 96);
    int tid = threadIdx.x;
    int h = ht * 8 + (tid >> 5);
    int w = tid & 31;

    const float* wbase = (co < 64) ? (wd + (size_t)co * 576)
                       : (co < 80) ? (wb + (size_t)(co - 64) * 576)
                                   : (wc + (size_t)(co - 80) * 576);

    int wm = (w + 31) & 31, wp = (w + 1) & 31;
    int hm = (h + 31) & 31, hp = (h + 1) & 31;
    const float* ub = u + (size_t)b * 64 * 1024;

    float acc = 0.f;
    #pragma unroll 4
    for (int ci = 0; ci < 64; ++ci) {
        const float* up = ub + ci * 1024;
        const float* r0 = up + hm * 32;
        const float* r1 = up + h * 32;
        const float* r2 = up + hp * 32;
        const float* wq = wbase + ci * 9;
        acc += wq[0] * r0[wm] + wq[1] * r0[w] + wq[2] * r0[wp]
             + wq[3] * r1[wm] + wq[4] * r1[w] + wq[5] * r1[wp]
             + wq[6] * r2[wm] + wq[7] * r2[w] + wq[8] * r2[wp];
    }

    int pix = h * 32 + w;
    if (co < 64) {
        float x = acc + bd[co] + dtp[0];
        float d = (x > 20.f) ? x : log1pf(__expf(x));   // softplus
        delta_out[((size_t)b * 64 + co) * 1024 + pix] = d;
    } else if (co < 80) {
        Bv_out[((size_t)b * 16 + (co - 64)) * 1024 + pix] = acc;
    } else {
        Cv_out[((size_t)b * 16 + (co - 80)) * 1024 + pix] = acc;
    }
}

// ---------------------------------------------------------------------------
// Kernel 2: state update + y reduction. One thread per (b, c, h, w).
// Grid: 4(b) * 64(c) * 4(h-tile) = 1024 blocks, 256 thr = 8 rows x 32 cols.
// ---------------------------------------------------------------------------
__global__ __launch_bounds__(256) void scan_kernel(
    const float* __restrict__ u, const float* __restrict__ s_prev,
    const float* __restrict__ logA, const float* __restrict__ Dp,
    const float* __restrict__ delta_in, const float* __restrict__ Bv,
    const float* __restrict__ Cv,
    float* __restrict__ y_out, float* __restrict__ s_next)
{
    int bx = blockIdx.x;
    int ht = bx & 3;
    int c  = (bx >> 2) & 63;
    int b  = bx >> 8;
    int tid = threadIdx.x;
    int h = ht * 8 + (tid >> 5);
    int w = tid & 31;
    int pix = h * 32 + w;

    float uv = u[((size_t)b * 64 + c) * 1024 + pix];
    float dv = delta_in[((size_t)b * 64 + c) * 1024 + pix];
    float y_skip = uv * Dp[c];

    float Abar[16], Bu[16], Creg[16];
    #pragma unroll
    for (int n = 0; n < 16; ++n) {
        float A  = -__expf(logA[c * 16 + n]);     // A = -exp(log_A_real)
        float ab = __expf(dv * A);                // A_bar
        Abar[n] = ab;
        float coef = (ab - 1.0f) / A;             // (A_bar - 1)/A
        Bu[n] = coef * Bv[((size_t)b * 16 + n) * 1024 + pix] * uv;
        Creg[n] = Cv[((size_t)b * 16 + n) * 1024 + pix];
    }

    #pragma unroll 1
    for (int i = 0; i < 9; ++i) {
        int vx = i / 3 - 1;
        int vy = i % 3 - 1;
        int hh = (h + vy + 32) & 31;
        int ww = (w + vx + 32) & 31;
        size_t chan = ((size_t)(b * 9 + i) * 64 + c) * 16;
        size_t base_in  = chan * 1024 + hh * 32 + ww;
        size_t base_out = chan * 1024 + pix;

        float y = 0.f;
        #pragma unroll
        for (int n = 0; n < 16; ++n) {
            float s  = s_prev[base_in + n * 1024];
            float sn = fmaf(Abar[n], s, Bu[n]);
            s_next[base_out + n * 1024] = sn;
            y = fmaf(sn, Creg[n], y);
        }
        y_out[((size_t)(b * 9 + i) * 64 + c) * 1024 + pix] = y + y_skip;
    }
}

extern "C" void kernel_launch(void* const* d_in, const int* in_sizes, int n_in,
                              void* d_out, int out_size, void* d_ws, size_t ws_size,
                              hipStream_t stream) {
    const float* u      = (const float*)d_in[0];
    const float* s_prev = (const float*)d_in[1];
    const float* wd     = (const float*)d_in[2];
    const float* bd     = (const float*)d_in[3];
    const float* wb     = (const float*)d_in[4];
    const float* wc     = (const float*)d_in[5];
    const float* logA   = (const float*)d_in[6];
    const float* Dp     = (const float*)d_in[7];
    const float* dtp    = (const float*)d_in[8];

    float* ws    = (float*)d_ws;
    float* delta = ws;                 // 4*64*1024   = 262144 floats
    float* Bv    = ws + 262144;        // 4*16*1024   =  65536 floats
    float* Cv    = ws + 327680;        // 4*16*1024   =  65536 floats

    float* y_out  = (float*)d_out;                         // 4*9*64*1024  = 2359296
    float* s_next = y_out + (size_t)NBATCH * NV * DM * 1024;  // 4*9*64*16*1024

    conv_kernel<<<dim3(4 * 96 * 4), dim3(256), 0, stream>>>(
        u, wd, bd, wb, wc, dtp, delta, Bv, Cv);
    scan_kernel<<<dim3(4 * 64 * 4), dim3(256), 0, stream>>>(
        u, s_prev, logA, Dp, delta, Bv, Cv, y_out, s_next);
}

// Round 2
// 120.804 us; speedup vs baseline: 1.2516x; 1.2516x over previous
//
#include <hip/hip_runtime.h>
#include <math.h>

#define NBATCH 4
#define NV 9
#define DM 64
#define DS 16
// H = W = 32, image = 1024 pixels

// ---------------------------------------------------------------------------
// Kernel 1: fused circular 3x3 convs. 96 "output channels":
//   co in [0,64)  -> delta conv (+bias +dt, softplus)
//   co in [64,80) -> B conv
//   co in [80,96) -> C conv
// Grid: 4(b) * 96(co) * 4(h-tile) = 1536 blocks, 256 thr = 8 rows x 32 cols.
// ---------------------------------------------------------------------------
__global__ __launch_bounds__(256) void conv_kernel(
    const float* __restrict__ u, const float* __restrict__ wd,
    const float* __restrict__ bd, const float* __restrict__ wb,
    const float* __restrict__ wc, const float* __restrict__ dtp,
    float* __restrict__ delta_out, float* __restrict__ Bv_out,
    float* __restrict__ Cv_out)
{
    int bx = blockIdx.x;
    int ht = bx & 3;
    int co = (bx >> 2) % 96;
    int b  = bx / (4 * 96);
    int tid = threadIdx.x;
    int h = ht * 8 + (tid >> 5);
    int w = tid & 31;

    const float* wbase = (co < 64) ? (wd + (size_t)co * 576)
                       : (co < 80) ? (wb + (size_t)(co - 64) * 576)
                                   : (wc + (size_t)(co - 80) * 576);

    int wm = (w + 31) & 31, wp = (w + 1) & 31;
    int hm = (h + 31) & 31, hp = (h + 1) & 31;
    const float* ub = u + (size_t)b * 64 * 1024;

    float acc = 0.f;
    #pragma unroll 4
    for (int ci = 0; ci < 64; ++ci) {
        const float* up = ub + ci * 1024;
        const float* r0 = up + hm * 32;
        const float* r1 = up + h * 32;
        const float* r2 = up + hp * 32;
        const float* wq = wbase + ci * 9;
        acc += wq[0] * r0[wm] + wq[1] * r0[w] + wq[2] * r0[wp]
             + wq[3] * r1[wm] + wq[4] * r1[w] + wq[5] * r1[wp]
             + wq[6] * r2[wm] + wq[7] * r2[w] + wq[8] * r2[wp];
    }

    int pix = h * 32 + w;
    if (co < 64) {
        float x = acc + bd[co] + dtp[0];
        float d = (x > 20.f) ? x : log1pf(__expf(x));   // softplus
        delta_out[((size_t)b * 64 + co) * 1024 + pix] = d;
    } else if (co < 80) {
        Bv_out[((size_t)b * 16 + (co - 64)) * 1024 + pix] = acc;
    } else {
        Cv_out[((size_t)b * 16 + (co - 80)) * 1024 + pix] = acc;
    }
}

// ---------------------------------------------------------------------------
// Kernel 2: state update + y reduction. One thread per (b, i, c, pix).
// Grid: 4(b) * 9(i) * 64(c) * 4(pix-tile) = 9216 blocks, 256 threads.
// A_bar / B_bar coefficients recomputed per-i (9x redundant) — exp is cheap,
// parallelism is not.
// ---------------------------------------------------------------------------
__global__ __launch_bounds__(256) void scan_kernel(
    const float* __restrict__ u, const float* __restrict__ s_prev,
    const float* __restrict__ logA, const float* __restrict__ Dp,
    const float* __restrict__ delta_in, const float* __restrict__ Bv,
    const float* __restrict__ Cv,
    float* __restrict__ y_out, float* __restrict__ s_next)
{
    int bx = blockIdx.x;
    int t  = bx & 3;
    int c  = (bx >> 2) & 63;
    int bi = bx >> 8;           // b*9 + i
    int i  = bi % 9;
    int b  = bi / 9;

    int tid = threadIdx.x;
    int pix = t * 256 + tid;
    int h = pix >> 5, w = pix & 31;

    int vx = i / 3 - 1;
    int vy = i % 3 - 1;
    int hh = (h + vy + 32) & 31;
    int ww = (w + vx + 32) & 31;

    float uv = u[(((size_t)b * 64 + c) << 10) + pix];
    float dv = delta_in[(((size_t)b * 64 + c) << 10) + pix];
    float y  = uv * Dp[c];

    size_t chan = ((size_t)bi * 64 + c) * 16;
    const float* sp  = s_prev + (chan << 10) + hh * 32 + ww;
    float*       sn  = s_next + (chan << 10) + pix;
    const float* bvp = Bv + (((size_t)b * 16) << 10) + pix;
    const float* cvp = Cv + (((size_t)b * 16) << 10) + pix;
    const float* la  = logA + c * 16;

    #pragma unroll
    for (int n = 0; n < 16; ++n) {
        float A    = -__expf(la[n]);                       // A = -exp(log_A_real)
        float ab   = __expf(dv * A);                       // A_bar
        float coef = (ab - 1.0f) * __builtin_amdgcn_rcpf(A);
        float bu   = coef * bvp[(size_t)n << 10] * uv;     // B_bar * u
        float s    = sp[(size_t)n << 10];
        float v    = fmaf(ab, s, bu);
        sn[(size_t)n << 10] = v;
        y = fmaf(v, cvp[(size_t)n << 10], y);
    }
    y_out[((size_t)bi * 64 + c) * 1024 + pix] = y;
}

extern "C" void kernel_launch(void* const* d_in, const int* in_sizes, int n_in,
                              void* d_out, int out_size, void* d_ws, size_t ws_size,
                              hipStream_t stream) {
    const float* u      = (const float*)d_in[0];
    const float* s_prev = (const float*)d_in[1];
    const float* wd     = (const float*)d_in[2];
    const float* bd     = (const float*)d_in[3];
    const float* wb     = (const float*)d_in[4];
    const float* wc     = (const float*)d_in[5];
    const float* logA   = (const float*)d_in[6];
    const float* Dp     = (const float*)d_in[7];
    const float* dtp    = (const float*)d_in[8];

    float* ws    = (float*)d_ws;
    float* delta = ws;                 // 4*64*1024   = 262144 floats
    float* Bv    = ws + 262144;        // 4*16*1024   =  65536 floats
    float* Cv    = ws + 327680;        // 4*16*1024   =  65536 floats

    float* y_out  = (float*)d_out;                            // 4*9*64*1024
    float* s_next = y_out + (size_t)NBATCH * NV * DM * 1024;  // 4*9*64*16*1024

    conv_kernel<<<dim3(4 * 96 * 4), dim3(256), 0, stream>>>(
        u, wd, bd, wb, wc, dtp, delta, Bv, Cv);
    scan_kernel<<<dim3(4 * 9 * 64 * 4), dim3(256), 0, stream>>>(
        u, s_prev, logA, Dp, delta, Bv, Cv, y_out, s_next);
}